// Round 2
// 499.397 us; speedup vs baseline: 1.0088x; 1.0088x over previous
//
#include <hip/hip_runtime.h>

#define DIM 4096
#define TOTAL 16384
#define WIDTH 4
#define STATE_LEN 3
#define BATCH 8
#define NSLOTS 256
#define TVEC (TOTAL / 4)                  // 4096 float4 per x row
#define NCONV_BLK ((DIM * TVEC) / 256)    // 65536 blocks for conv part
#define SROW (DIM * STATE_LEN)            // 12288 floats per slot row-block
#define S4_PER_SLOT (SROW / 4)            // 3072 float4 per slot
#define NSTATE4 (NSLOTS * S4_PER_SLOT)    // 786432 float4 total states
#define NSTATE_BLK (NSTATE4 / 256)        // 3072 blocks for state part

typedef float floatx4 __attribute__((ext_vector_type(4)));   // clang-native vec4 (nontemporal-compatible)

// Single fused kernel:
//   blocks [0, NCONV_BLK)                    : conv output (float4 per thread)
//   blocks [NCONV_BLK, NCONV_BLK+NSTATE_BLK) : full out_states write
//     (copy from cs for untouched slots, recompute for the BATCH touched slots)
__global__ __launch_bounds__(256) void fused_kernel(
    const float* __restrict__ x, const float* __restrict__ weight,
    const float* __restrict__ cs, const int* __restrict__ qsl,
    const int* __restrict__ cache_indices, const int* __restrict__ init_mode,
    const int* __restrict__ pad_p, const int* __restrict__ res_p,
    float* __restrict__ out, float* __restrict__ out_states)
{
    __shared__ int s_qsl[BATCH + 1];
    __shared__ int s_ci[BATCH];
    __shared__ int s_im[BATCH];
    __shared__ int s_map[NSLOTS];
    __shared__ int s_pad, s_res;

    if (blockIdx.x < NCONV_BLK) {
        // ---------------- conv part ----------------
        if (threadIdx.x < BATCH + 1) s_qsl[threadIdx.x] = qsl[threadIdx.x];
        if (threadIdx.x >= 32 && threadIdx.x < 32 + BATCH) s_ci[threadIdx.x - 32] = cache_indices[threadIdx.x - 32];
        if (threadIdx.x >= 64 && threadIdx.x < 64 + BATCH) s_im[threadIdx.x - 64] = init_mode[threadIdx.x - 64];
        if (threadIdx.x == 96) s_pad = pad_p[0];
        if (threadIdx.x == 97) s_res = res_p[0];
        __syncthreads();

        unsigned v = blockIdx.x * 256u + threadIdx.x;   // global float4 index
        int d  = v >> 12;            // v / TVEC
        int tv = v & (TVEC - 1);
        int t0 = tv << 2;

        const floatx4* xr = (const floatx4*)(x + (size_t)d * TOTAL);
        floatx4 cur = xr[tv];
        floatx4 prev = (floatx4){0.f, 0.f, 0.f, 0.f};
        if (tv > 0) prev = xr[tv - 1];
        // win[3+i] = x[t0+i]; x[t-dd] = win[3+i-dd]
        float win[7] = {prev.y, prev.z, prev.w, cur.x, cur.y, cur.z, cur.w};

        floatx4 w = ((const floatx4*)weight)[d];   // uniform within block
        if (s_res) w.w += 1.0f;                    // fold residual into the x[t] tap

        int seg = 0;
        float res4[4];
        #pragma unroll
        for (int i = 0; i < 4; i++) {
            int t = t0 + i;
            while (seg + 1 < BATCH && t >= s_qsl[seg + 1]) seg++;
            int p = t - s_qsl[seg];
            float xt = win[3 + i];
            float acc;
            if (p >= 3) {
                // fast path: everything from x
                acc = w.x * win[i] + w.y * win[i + 1] + w.z * win[i + 2] + w.w * xt;
            } else {
                int raw = s_ci[seg];
                bool valid = (raw != s_pad);
                int slot = valid ? raw : 0;
                bool use_init = valid && (s_im[seg] != 0);
                const float* csrow = cs + ((size_t)slot * DIM + d) * STATE_LEN;
                float xm1 = (p >= 1) ? win[i + 2] : (use_init ? csrow[2 + p] : 0.f);
                float xm2 = (p >= 2) ? win[i + 1] : (use_init ? csrow[1 + p] : 0.f);
                float xm3 =                          (use_init ? csrow[0 + p] : 0.f);
                acc = w.x * xm3 + w.y * xm2 + w.z * xm1 + w.w * xt;
            }
            res4[i] = acc;
        }
        floatx4 rv = (floatx4){res4[0], res4[1], res4[2], res4[3]};
        __builtin_nontemporal_store(rv, (floatx4*)(out + (size_t)d * TOTAL) + tv);
    } else {
        // ---------------- states part ----------------
        s_map[threadIdx.x] = -1;                      // blockDim == NSLOTS == 256
        if (threadIdx.x < BATCH + 1) s_qsl[threadIdx.x] = qsl[threadIdx.x];
        if (threadIdx.x >= 32 && threadIdx.x < 32 + BATCH) s_im[threadIdx.x - 32] = init_mode[threadIdx.x - 32];
        __syncthreads();
        if (threadIdx.x < BATCH) {
            int raw = cache_indices[threadIdx.x];
            if (raw != pad_p[0] && raw >= 0 && raw < NSLOTS) s_map[raw] = threadIdx.x;
        }
        __syncthreads();

        int f = (blockIdx.x - NCONV_BLK) * 256 + threadIdx.x;   // global float4 index
        int slot = f / S4_PER_SLOT;
        int r4   = f - slot * S4_PER_SLOT;
        int b = s_map[slot];
        floatx4 cv = ((const floatx4*)cs)[f];
        if (b < 0) {
            // untouched (or pad-dropped) slot: straight copy
            __builtin_nontemporal_store(cv, (floatx4*)out_states + f);
        } else {
            int start = s_qsl[b], end = s_qsl[b + 1];
            int L = end - start;
            bool init = (s_im[b] != 0);
            int base = r4 * 4;                   // float index within slot block
            float r[4];
            #pragma unroll
            for (int e = 0; e < 4; e++) {
                int idx = base + e;              // = d*3 + j
                int d = idx / 3;
                int j = idx - d * 3;
                int gx = end + j - STATE_LEN;
                float val;
                if (gx >= start) {
                    val = x[(size_t)d * TOTAL + gx];
                } else if (init) {
                    int sidx = L + j;            // gx<start => L+j<3, but clamp anyway
                    if (sidx > STATE_LEN - 1) sidx = STATE_LEN - 1;
                    val = cs[(size_t)slot * SROW + (idx - j) + sidx];
                } else {
                    val = 0.f;
                }
                r[e] = val;
            }
            floatx4 rv = (floatx4){r[0], r[1], r[2], r[3]};
            __builtin_nontemporal_store(rv, (floatx4*)out_states + f);
        }
    }
}

extern "C" void kernel_launch(void* const* d_in, const int* in_sizes, int n_in,
                              void* d_out, int out_size, void* d_ws, size_t ws_size,
                              hipStream_t stream) {
    const float* x      = (const float*)d_in[0];
    const float* weight = (const float*)d_in[1];
    const float* cs     = (const float*)d_in[2];
    const int*   qsl    = (const int*)d_in[3];
    const int*   ci     = (const int*)d_in[4];
    const int*   im     = (const int*)d_in[5];
    const int*   pad    = (const int*)d_in[6];
    const int*   res    = (const int*)d_in[7];

    float* out        = (float*)d_out;
    float* out_states = out + (size_t)DIM * TOTAL;

    fused_kernel<<<NCONV_BLK + NSTATE_BLK, 256, 0, stream>>>(
        x, weight, cs, qsl, ci, im, pad, res, out, out_states);
}